// Round 6
// baseline (128.638 us; speedup 1.0000x reference)
//
#include <hip/hip_runtime.h>
#include <stdint.h>
#include <stddef.h>

typedef __bf16 bf16_t;
typedef __bf16 bf16x8 __attribute__((ext_vector_type(8)));
typedef __bf16 bf16x4 __attribute__((ext_vector_type(4)));
typedef float f32x4 __attribute__((ext_vector_type(4)));

#define VMW(n) asm volatile("s_waitcnt vmcnt(" #n ")" ::: "memory")
#define LGKM0 asm volatile("s_waitcnt lgkmcnt(0)" ::: "memory")
#define CFENCE asm volatile("" ::: "memory")
#define RAWBAR              \
  do {                      \
    __builtin_amdgcn_s_barrier(); \
    CFENCE;                 \
  } while (0)

__device__ __forceinline__ void gload_lds16(const void* g, void* l) {
  __builtin_amdgcn_global_load_lds(
      (const __attribute__((address_space(1))) uint32_t*)g,
      (__attribute__((address_space(3))) uint32_t*)l, 16, 0, 0);
}

// ---------------- w2s: w2s[r*256+m] = sum_n w2[((r*256+m)*64)+n] ----------------
__global__ __launch_bounds__(256) void w2s_k(const float* __restrict__ w2,
                                             float* __restrict__ w2s) {
  const int r = blockIdx.x, m = threadIdx.x;
  const float4* p = (const float4*)(w2 + ((size_t)(r * 256 + m)) * 64);
  float s = 0.f;
#pragma unroll
  for (int i = 0; i < 16; ++i) {
    float4 v = p[i];
    s += (v.x + v.y) + (v.z + v.w);
  }
  w2s[r * 256 + m] = s;
}

// ---------------- merged prep (depends only on w2s, w1, w3, b1, b2) ----------------
// blocks 0..255:   w1t[m*4096+k] = bf16(w1[k*256+m] * w2s[(k&63)*256+m])
// blocks 256..511: w3pt[(o*64+r)*256+m] = bf16(w3[m*4096 + r*64 + o])
// block 512:       c2[m] = sum_r bias1[r]*w2s[r*256+m] + 64*bias2[m]
__global__ __launch_bounds__(256) void prep_k(
    const float* __restrict__ w1, const float* __restrict__ w3,
    const float* __restrict__ w2s, const float* __restrict__ bias1,
    const float* __restrict__ bias2, bf16_t* __restrict__ w1t,
    bf16_t* __restrict__ w3pt, float* __restrict__ c2) {
  __shared__ float lds[64][65];
  const int b = blockIdx.x;
  const int t = threadIdx.x;
  if (b == 512) {
    float s = 64.f * bias2[t];
#pragma unroll 8
    for (int r = 0; r < 64; ++r) s += bias1[r] * w2s[r * 256 + t];
    c2[t] = s;
    return;
  }
  if (b < 256) {
    const int k0 = (b >> 2) * 64;
    const int mt = (b & 3) * 64;
#pragma unroll
    for (int it = 0; it < 16; ++it) {
      int idx = t + it * 256;
      int kl = idx >> 6, ml = idx & 63;
      int k = k0 + kl;
      lds[kl][ml] = w1[(size_t)k * 256 + mt + ml] * w2s[(k & 63) * 256 + mt + ml];
    }
    __syncthreads();
#pragma unroll
    for (int it = 0; it < 16; ++it) {
      int idx = t + it * 256;
      int ml = idx >> 6, kl = idx & 63;
      w1t[(size_t)(mt + ml) * 4096 + k0 + kl] = (bf16_t)lds[kl][ml];
    }
    return;
  }
  const int b2 = b - 256;
  const int r = b2 & 63;
  const int mt = (b2 >> 6) * 64;
#pragma unroll
  for (int it = 0; it < 16; ++it) {
    int idx = t + it * 256;
    int ml = idx >> 6, o = idx & 63;
    lds[ml][o] = w3[(size_t)(mt + ml) * 4096 + r * 64 + o];
  }
  __syncthreads();
#pragma unroll
  for (int it = 0; it < 16; ++it) {
    int idx = t + it * 256;
    int o = idx >> 6, ml = idx & 63;
    w3pt[(size_t)(o * 64 + r) * 256 + mt + ml] = (bf16_t)lds[ml][o];
  }
}

// ---------------- GEMM1 (full K): S[t,n] = bf16( sum_{k=0..4095} bf16(X[t,k])*W1T[n,k] + c2[n] )
// grid 256 = 8 xcd x 32 mtiles (rows xcd*1024..+1023); 512 threads = 8 waves, 1M x 8N,
// wave tile 32x32; BM=32, BN=256, BK=64, 64 K-steps; counted-vmcnt 2-deep pipeline
__global__ __launch_bounds__(512, 2) void gemm1_k(
    const float* __restrict__ X, const bf16_t* __restrict__ W1T,
    const float* __restrict__ c2, bf16_t* __restrict__ S) {
  __shared__ __align__(16) bf16_t lA[2][32 * 64];
  __shared__ __align__(16) bf16_t lB[2][256 * 64];
  const int tid = threadIdx.x;
  const int lane = tid & 63;
  const int wv = tid >> 6;  // 0..7 = N-slot
  const int bid = (int)blockIdx.x;
  const int mtile = (bid & 7) * 32 + (bid >> 3);  // XCD x owns rows x*1024..+1023
  const size_t m0 = (size_t)mtile * 32;
  const int ar = tid >> 4;  // 0..31 A-stage row
  const int ac = tid & 15;  // A-stage col group (4 floats)

  f32x4 acc[2][2];
#pragma unroll
  for (int i = 0; i < 2; ++i)
#pragma unroll
    for (int j = 0; j < 2; ++j) acc[i][j] = (f32x4){0.f, 0.f, 0.f, 0.f};

  float4 aX, aY;  // 2-deep A prefetch (1 float4/thread)

  auto issueA = [&](float4& dst, int kt) {
    dst = *(const float4*)(X + (m0 + ar) * 4096 + (size_t)(kt * 64 + ac * 4));
  };
  auto writeA = [&](const float4& src, int buf) {
    int off = ar * 128 + ((ac * 8) ^ ((ar & 7) << 4));
    bf16x4 v;
    v[0] = (bf16_t)src.x;
    v[1] = (bf16_t)src.y;
    v[2] = (bf16_t)src.z;
    v[3] = (bf16_t)src.w;
    *(bf16x4*)((char*)(&lA[buf][0]) + off) = v;
  };
  auto issueB = [&](int buf, int kt) {
#pragma unroll
    for (int i = 0; i < 4; ++i) {
      int row = wv * 32 + i * 8 + (lane >> 3);
      int srckb = ((lane & 7) * 16) ^ ((row & 7) << 4);
      const char* src = (const char*)W1T + (size_t)row * 8192 + (size_t)(kt * 64) * 2 + srckb;
      char* dst = (char*)(&lB[buf][0]) + (wv * 32 + i * 8) * 128;  // wave-uniform base
      gload_lds16(src, dst);
    }
  };
  auto compute = [&](int buf) {
#pragma unroll
    for (int kk = 0; kk < 2; ++kk) {
      const int kb = kk * 64 + ((lane >> 4) * 16);
      bf16x8 af[2], bfr[2];
#pragma unroll
      for (int mf = 0; mf < 2; ++mf) {
        int row = mf * 16 + (lane & 15);
        int off = row * 128 + (kb ^ ((row & 7) << 4));
        af[mf] = *(const bf16x8*)((const char*)(&lA[buf][0]) + off);
      }
#pragma unroll
      for (int nf = 0; nf < 2; ++nf) {
        int row = wv * 32 + nf * 16 + (lane & 15);
        int off = row * 128 + (kb ^ ((row & 7) << 4));
        bfr[nf] = *(const bf16x8*)((const char*)(&lB[buf][0]) + off);
      }
#pragma unroll
      for (int mf = 0; mf < 2; ++mf)
#pragma unroll
        for (int nf = 0; nf < 2; ++nf)
          acc[mf][nf] = __builtin_amdgcn_mfma_f32_16x16x32_bf16(af[mf], bfr[nf], acc[mf][nf], 0, 0, 0);
    }
  };

  // prologue: in flight after: B0[4],A0[1],B1[4],A1[1]
  issueB(0, 0);
  CFENCE;
  issueA(aX, 0);
  CFENCE;
  issueB(1, 1);
  CFENCE;
  issueA(aY, 1);
  CFENCE;
  VMW(5);  // tile 0 landed; B1+A1 (5 ops) in flight
  writeA(aX, 0);
  LGKM0;
  RAWBAR;

  // steady: at top of iter t: buf[t&1] ready; in flight B(t+1)[4]+A(t+1)[1]
#pragma unroll 1
  for (int t2 = 0; t2 < 62; t2 += 2) {
    // even t = t2: consume buf0
    compute(0);
    RAWBAR;  // all waves done reading buf0
    issueB(0, t2 + 2);
    CFENCE;
    issueA(aX, t2 + 2);
    CFENCE;
    VMW(5);  // B(t+1)+A(t+1) landed; B(t+2)+A(t+2) flying
    writeA(aY, 1);
    LGKM0;
    RAWBAR;
    // odd t = t2+1: consume buf1
    compute(1);
    RAWBAR;
    issueB(1, t2 + 3);
    CFENCE;
    issueA(aY, t2 + 3);
    CFENCE;
    VMW(5);
    writeA(aX, 0);
    LGKM0;
    RAWBAR;
  }
  // t = 62
  compute(0);
  RAWBAR;
  VMW(0);  // B63+A63 landed
  writeA(aY, 1);
  LGKM0;
  RAWBAR;
  // t = 63
  compute(1);

  // epilogue: S = bf16(acc + c2)
#pragma unroll
  for (int nf = 0; nf < 2; ++nf) {
    int col = wv * 32 + nf * 16 + (lane & 15);
    float cadd = c2[col];
#pragma unroll
    for (int mf = 0; mf < 2; ++mf) {
#pragma unroll
      for (int q = 0; q < 4; ++q) {
        int row = mf * 16 + (lane >> 4) * 4 + q;
        S[(m0 + row) * 256 + (size_t)col] = (bf16_t)(acc[mf][nf][q] + cadd);
      }
    }
  }
}

// ---------------- GEMM2: OUT[t, j] = sum_{m=0..255} S[t,m] * W3pT[j, m] + bias3[j&63]
// grid 1024 = 8 xcd x 8 mt x 16 nt; 512 threads = 8 waves (2M x 4N), wave tile 64x64
// BM=128, BN=256, BK=64, NT=4; both operands via global_load_lds; counted vmcnt
__global__ __launch_bounds__(512, 2) void gemm2_k(
    const bf16_t* __restrict__ S, const bf16_t* __restrict__ W3pT,
    const float* __restrict__ bias3, float* __restrict__ OUT) {
  __shared__ __align__(16) bf16_t lA[2][128 * 64];
  __shared__ __align__(16) bf16_t lB[2][256 * 64];
  const int tid = threadIdx.x;
  const int lane = tid & 63;
  const int wv = tid >> 6;
  const int bid = (int)blockIdx.x;
  const int xcd = bid & 7;
  const int rest = bid >> 3;            // 0..127
  const int mt = xcd * 8 + (rest >> 4); // rows xcd*1024..+1023 (matches gemm1 writer)
  const int nt = rest & 15;
  const size_t m0 = (size_t)mt * 128;
  const int n0 = nt * 256;
  const int wm = wv >> 2, wn = wv & 3;

  f32x4 acc[4][4];
#pragma unroll
  for (int i = 0; i < 4; ++i)
#pragma unroll
    for (int j = 0; j < 4; ++j) acc[i][j] = (f32x4){0.f, 0.f, 0.f, 0.f};

  auto stage = [&](int buf, int kt) {
#pragma unroll
    for (int i = 0; i < 2; ++i) {
      int row = wv * 16 + i * 8 + (lane >> 3);
      int srckb = ((lane & 7) * 16) ^ ((row & 7) << 4);
      const char* srcA = (const char*)S + (m0 + row) * 512 + (size_t)(kt * 128) + srckb;
      char* dstA = (char*)(&lA[buf][0]) + (wv * 16 + i * 8) * 128;
      gload_lds16(srcA, dstA);
    }
#pragma unroll
    for (int i = 0; i < 4; ++i) {
      int row = wv * 32 + i * 8 + (lane >> 3);
      int srckb = ((lane & 7) * 16) ^ ((row & 7) << 4);
      const char* srcB = (const char*)W3pT + (size_t)(n0 + row) * 512 + (size_t)(kt * 128) + srckb;
      char* dstB = (char*)(&lB[buf][0]) + (wv * 32 + i * 8) * 128;
      gload_lds16(srcB, dstB);
    }
  };
  auto compute = [&](int buf) {
#pragma unroll
    for (int kk = 0; kk < 2; ++kk) {
      const int kb = kk * 64 + ((lane >> 4) * 16);
      bf16x8 af[4], bfr[4];
#pragma unroll
      for (int mf = 0; mf < 4; ++mf) {
        int row = wm * 64 + mf * 16 + (lane & 15);
        int off = row * 128 + (kb ^ ((row & 7) << 4));
        af[mf] = *(const bf16x8*)((const char*)(&lA[buf][0]) + off);
      }
#pragma unroll
      for (int nf = 0; nf < 4; ++nf) {
        int row = wn * 64 + nf * 16 + (lane & 15);
        int off = row * 128 + (kb ^ ((row & 7) << 4));
        bfr[nf] = *(const bf16x8*)((const char*)(&lB[buf][0]) + off);
      }
#pragma unroll
      for (int mf = 0; mf < 4; ++mf)
#pragma unroll
        for (int nf = 0; nf < 4; ++nf)
          acc[mf][nf] = __builtin_amdgcn_mfma_f32_16x16x32_bf16(af[mf], bfr[nf], acc[mf][nf], 0, 0, 0);
    }
  };

  // NT=4, fully peeled, counted vmcnt (6 loads per stage)
  stage(0, 0);
  CFENCE;
  stage(1, 1);
  CFENCE;
  VMW(6);  // tile 0 landed, tile 1 flying
  RAWBAR;
  compute(0);
  RAWBAR;
  stage(0, 2);
  CFENCE;
  VMW(6);
  RAWBAR;
  compute(1);
  RAWBAR;
  stage(1, 3);
  CFENCE;
  VMW(6);
  RAWBAR;
  compute(0);
  RAWBAR;
  VMW(0);
  RAWBAR;
  compute(1);

#pragma unroll
  for (int nf = 0; nf < 4; ++nf) {
    int jcol = wn * 64 + nf * 16 + (lane & 15);
    float b3 = bias3[jcol & 63];
    int j = n0 + jcol;
#pragma unroll
    for (int mf = 0; mf < 4; ++mf) {
#pragma unroll
      for (int q = 0; q < 4; ++q) {
        size_t row = m0 + (size_t)(wm * 64 + mf * 16 + (lane >> 4) * 4 + q);
        OUT[row * 4096 + j] = acc[mf][nf][q] + b3;
      }
    }
  }
}

extern "C" void kernel_launch(void* const* d_in, const int* in_sizes, int n_in,
                              void* d_out, int out_size, void* d_ws, size_t ws_size,
                              hipStream_t stream) {
  (void)in_sizes; (void)n_in; (void)out_size; (void)ws_size;
  const float* x  = (const float*)d_in[0];
  const float* w1 = (const float*)d_in[1];
  const float* w2 = (const float*)d_in[2];
  const float* w3 = (const float*)d_in[3];
  const float* b1 = (const float*)d_in[4];
  const float* b2 = (const float*)d_in[5];
  const float* b3 = (const float*)d_in[6];
  float* out = (float*)d_out;
  char* ws = (char*)d_ws;

  // workspace layout
  float*  w2s  = (float*)(ws + 0);                   // 64 KB
  float*  c2   = (float*)(ws + 65536);               // 1 KB (+pad)
  bf16_t* w1t  = (bf16_t*)(ws + 69632);              // 2 MB  [256][4096] bf16
  bf16_t* w3pt = (bf16_t*)(ws + 69632 + 2097152);    // 2 MB  [4096][256] bf16
  bf16_t* S    = (bf16_t*)(ws + 69632 + 2 * 2097152);// 4 MB  [8192][256] bf16

  w2s_k<<<64, 256, 0, stream>>>(w2, w2s);
  prep_k<<<513, 256, 0, stream>>>(w1, w3, w2s, b1, b2, w1t, w3pt, c2);
  gemm1_k<<<256, 512, 0, stream>>>(x, w1t, c2, S);
  gemm2_k<<<1024, 512, 0, stream>>>(S, w3pt, b3, out);
}

// Round 7
// 123.323 us; speedup vs baseline: 1.0431x; 1.0431x over previous
//
#include <hip/hip_runtime.h>
#include <stdint.h>
#include <stddef.h>

typedef __bf16 bf16_t;
typedef __bf16 bf16x8 __attribute__((ext_vector_type(8)));
typedef __bf16 bf16x4 __attribute__((ext_vector_type(4)));
typedef float f32x4 __attribute__((ext_vector_type(4)));

#define VMW(n) asm volatile("s_waitcnt vmcnt(" #n ")" ::: "memory")
#define CFENCE asm volatile("" ::: "memory")
#define RAWBAR              \
  do {                      \
    __builtin_amdgcn_s_barrier(); \
    CFENCE;                 \
  } while (0)

__device__ __forceinline__ void gload_lds16(const void* g, void* l) {
  __builtin_amdgcn_global_load_lds(
      (const __attribute__((address_space(1))) uint32_t*)g,
      (__attribute__((address_space(3))) uint32_t*)l, 16, 0, 0);
}

// ---------------- w2s: w2s[r*256+m] = sum_n w2[((r*256+m)*64)+n] ----------------
__global__ __launch_bounds__(256) void w2s_k(const float* __restrict__ w2,
                                             float* __restrict__ w2s) {
  const int r = blockIdx.x, m = threadIdx.x;
  const float4* p = (const float4*)(w2 + ((size_t)(r * 256 + m)) * 64);
  float s = 0.f;
#pragma unroll
  for (int i = 0; i < 16; ++i) {
    float4 v = p[i];
    s += (v.x + v.y) + (v.z + v.w);
  }
  w2s[r * 256 + m] = s;
}

// ---------------- merged prep ----------------
// blocks 0..255:   w1t[m*4096+k] = bf16(w1[k*256+m] * w2s[(k&63)*256+m])
// blocks 256..511: w3pt[(o*64+r)*256+m] = bf16(w3[m*4096 + r*64 + o])
// block 512:       c2[m] = sum_r bias1[r]*w2s[r*256+m] + 64*bias2[m]
__global__ __launch_bounds__(256) void prep_k(
    const float* __restrict__ w1, const float* __restrict__ w3,
    const float* __restrict__ w2s, const float* __restrict__ bias1,
    const float* __restrict__ bias2, bf16_t* __restrict__ w1t,
    bf16_t* __restrict__ w3pt, float* __restrict__ c2) {
  __shared__ float lds[64][65];
  const int b = blockIdx.x;
  const int t = threadIdx.x;
  if (b == 512) {
    float s = 64.f * bias2[t];
#pragma unroll 8
    for (int r = 0; r < 64; ++r) s += bias1[r] * w2s[r * 256 + t];
    c2[t] = s;
    return;
  }
  if (b < 256) {
    const int k0 = (b >> 2) * 64;
    const int mt = (b & 3) * 64;
#pragma unroll
    for (int it = 0; it < 16; ++it) {
      int idx = t + it * 256;
      int kl = idx >> 6, ml = idx & 63;
      int k = k0 + kl;
      lds[kl][ml] = w1[(size_t)k * 256 + mt + ml] * w2s[(k & 63) * 256 + mt + ml];
    }
    __syncthreads();
#pragma unroll
    for (int it = 0; it < 16; ++it) {
      int idx = t + it * 256;
      int ml = idx >> 6, kl = idx & 63;
      w1t[(size_t)(mt + ml) * 4096 + k0 + kl] = (bf16_t)lds[kl][ml];
    }
    return;
  }
  const int b2 = b - 256;
  const int r = b2 & 63;
  const int mt = (b2 >> 6) * 64;
#pragma unroll
  for (int it = 0; it < 16; ++it) {
    int idx = t + it * 256;
    int ml = idx >> 6, o = idx & 63;
    lds[ml][o] = w3[(size_t)(mt + ml) * 4096 + r * 64 + o];
  }
  __syncthreads();
#pragma unroll
  for (int it = 0; it < 16; ++it) {
    int idx = t + it * 256;
    int o = idx >> 6, ml = idx & 63;
    w3pt[(size_t)(o * 64 + r) * 256 + mt + ml] = (bf16_t)lds[ml][o];
  }
}

// ---------------- GEMM1 (full K, small blocks for TLP) ----------------
// S[t,n] = bf16( sum_{k} bf16(X[t,k])*W1T[n,k] + c2[n] )
// grid 512 = 8 xcd x (16 mt x 4 nt, nt fastest); 256 thr = 4 waves (2M x 2N), wave 32x32
// BM=64, BN=64, BK=64, 64 K-steps; LDS 32KB -> ~5 blocks/CU; m97 2-barrier loop
__global__ __launch_bounds__(256, 4) void gemm1_k(
    const float* __restrict__ X, const bf16_t* __restrict__ W1T,
    const float* __restrict__ c2, bf16_t* __restrict__ S) {
  __shared__ __align__(16) bf16_t lA[2][64 * 64];
  __shared__ __align__(16) bf16_t lB[2][64 * 64];
  const int tid = threadIdx.x;
  const int lane = tid & 63;
  const int wv = tid >> 6;  // 0..3
  const int bid = (int)blockIdx.x;
  const int xcd = bid & 7;
  const int rest = bid >> 3;             // 0..63
  const int mtile = xcd * 16 + (rest >> 2);  // XCD x owns rows x*1024..+1023
  const int n0 = (rest & 3) * 64;            // nt cycles fastest -> X L2 reuse
  const size_t m0 = (size_t)mtile * 64;
  const int wm = wv >> 1, wn = wv & 1;   // 2M x 2N
  const int ar = tid >> 2;               // 0..63 A-stage row
  const int acg = tid & 3;               // A-stage col slot

  f32x4 acc[2][2];
#pragma unroll
  for (int i = 0; i < 2; ++i)
#pragma unroll
    for (int j = 0; j < 2; ++j) acc[i][j] = (f32x4){0.f, 0.f, 0.f, 0.f};

  float4 aR[4];  // A staging: 4 float4/thread (row ar, f4-slots acg+4j)

  auto issueA = [&](int kt) {
#pragma unroll
    for (int j = 0; j < 4; ++j) {
      int f4 = acg + j * 4;
      aR[j] = *(const float4*)(X + (m0 + ar) * 4096 + (size_t)(kt * 64 + f4 * 4));
    }
  };
  auto writeA = [&](int buf) {
#pragma unroll
    for (int j = 0; j < 4; ++j) {
      int f4 = acg + j * 4;
      int off = ar * 128 + ((f4 * 8) ^ ((ar & 7) << 4));
      bf16x4 v;
      v[0] = (bf16_t)aR[j].x;
      v[1] = (bf16_t)aR[j].y;
      v[2] = (bf16_t)aR[j].z;
      v[3] = (bf16_t)aR[j].w;
      *(bf16x4*)((char*)(&lA[buf][0]) + off) = v;
    }
  };
  auto issueB = [&](int buf, int kt) {
#pragma unroll
    for (int i = 0; i < 2; ++i) {
      int row = wv * 16 + i * 8 + (lane >> 3);
      int srckb = ((lane & 7) * 16) ^ ((row & 7) << 4);
      const char* src = (const char*)W1T + (size_t)(n0 + row) * 8192 + (size_t)(kt * 128) + srckb;
      char* dst = (char*)(&lB[buf][0]) + (wv * 16 + i * 8) * 128;  // wave-uniform base
      gload_lds16(src, dst);
    }
  };
  auto compute = [&](int buf) {
#pragma unroll
    for (int kk = 0; kk < 2; ++kk) {
      const int kb = kk * 64 + ((lane >> 4) * 16);
      bf16x8 af[2], bfr[2];
#pragma unroll
      for (int mf = 0; mf < 2; ++mf) {
        int row = wm * 32 + mf * 16 + (lane & 15);
        int off = row * 128 + (kb ^ ((row & 7) << 4));
        af[mf] = *(const bf16x8*)((const char*)(&lA[buf][0]) + off);
      }
#pragma unroll
      for (int nf = 0; nf < 2; ++nf) {
        int row = wn * 32 + nf * 16 + (lane & 15);
        int off = row * 128 + (kb ^ ((row & 7) << 4));
        bfr[nf] = *(const bf16x8*)((const char*)(&lB[buf][0]) + off);
      }
#pragma unroll
      for (int mf = 0; mf < 2; ++mf)
#pragma unroll
        for (int nf = 0; nf < 2; ++nf)
          acc[mf][nf] = __builtin_amdgcn_mfma_f32_16x16x32_bf16(af[mf], bfr[nf], acc[mf][nf], 0, 0, 0);
    }
  };

  // prologue
  issueA(0);
  issueB(0, 0);
  writeA(0);         // compiler inserts vmcnt wait on A-loads
  __syncthreads();   // drains B(0) gload_lds

  // m97 2-barrier loop; cross-block TLP hides the drain
#pragma unroll 1
  for (int kt = 0; kt < 64; ++kt) {
    int cur = kt & 1;
    bool more = (kt + 1) < 64;
    if (more) {
      issueA(kt + 1);          // start X read early (HBM)
      issueB(cur ^ 1, kt + 1); // async direct-to-LDS
    }
    compute(cur);
    if (more) writeA(cur ^ 1);
    __syncthreads();
  }

  // epilogue: S = bf16(acc + c2)
#pragma unroll
  for (int nf = 0; nf < 2; ++nf) {
    int col = n0 + wn * 32 + nf * 16 + (lane & 15);
    float cadd = c2[col];
#pragma unroll
    for (int mf = 0; mf < 2; ++mf) {
#pragma unroll
      for (int q = 0; q < 4; ++q) {
        int row = wm * 32 + mf * 16 + (lane >> 4) * 4 + q;
        S[(m0 + row) * 256 + (size_t)col] = (bf16_t)(acc[mf][nf][q] + cadd);
      }
    }
  }
}

// ---------------- GEMM2: OUT[t, j] = sum_{m=0..255} S[t,m] * W3pT[j, m] + bias3[j&63]
// grid 1024 = 8 xcd x 8 mt x 16 nt; 512 threads = 8 waves (2M x 4N), wave tile 64x64
// BM=128, BN=256, BK=64, NT=4; both operands via global_load_lds; counted vmcnt
__global__ __launch_bounds__(512, 2) void gemm2_k(
    const bf16_t* __restrict__ S, const bf16_t* __restrict__ W3pT,
    const float* __restrict__ bias3, float* __restrict__ OUT) {
  __shared__ __align__(16) bf16_t lA[2][128 * 64];
  __shared__ __align__(16) bf16_t lB[2][256 * 64];
  const int tid = threadIdx.x;
  const int lane = tid & 63;
  const int wv = tid >> 6;
  const int bid = (int)blockIdx.x;
  const int xcd = bid & 7;
  const int rest = bid >> 3;            // 0..127
  const int mt = xcd * 8 + (rest >> 4); // rows xcd*1024..+1023 (matches gemm1 writer)
  const int nt = rest & 15;
  const size_t m0 = (size_t)mt * 128;
  const int n0 = nt * 256;
  const int wm = wv >> 2, wn = wv & 3;

  f32x4 acc[4][4];
#pragma unroll
  for (int i = 0; i < 4; ++i)
#pragma unroll
    for (int j = 0; j < 4; ++j) acc[i][j] = (f32x4){0.f, 0.f, 0.f, 0.f};

  auto stage = [&](int buf, int kt) {
#pragma unroll
    for (int i = 0; i < 2; ++i) {
      int row = wv * 16 + i * 8 + (lane >> 3);
      int srckb = ((lane & 7) * 16) ^ ((row & 7) << 4);
      const char* srcA = (const char*)S + (m0 + row) * 512 + (size_t)(kt * 128) + srckb;
      char* dstA = (char*)(&lA[buf][0]) + (wv * 16 + i * 8) * 128;
      gload_lds16(srcA, dstA);
    }
#pragma unroll
    for (int i = 0; i < 4; ++i) {
      int row = wv * 32 + i * 8 + (lane >> 3);
      int srckb = ((lane & 7) * 16) ^ ((row & 7) << 4);
      const char* srcB = (const char*)W3pT + (size_t)(n0 + row) * 512 + (size_t)(kt * 128) + srckb;
      char* dstB = (char*)(&lB[buf][0]) + (wv * 32 + i * 8) * 128;
      gload_lds16(srcB, dstB);
    }
  };
  auto compute = [&](int buf) {
#pragma unroll
    for (int kk = 0; kk < 2; ++kk) {
      const int kb = kk * 64 + ((lane >> 4) * 16);
      bf16x8 af[4], bfr[4];
#pragma unroll
      for (int mf = 0; mf < 4; ++mf) {
        int row = wm * 64 + mf * 16 + (lane & 15);
        int off = row * 128 + (kb ^ ((row & 7) << 4));
        af[mf] = *(const bf16x8*)((const char*)(&lA[buf][0]) + off);
      }
#pragma unroll
      for (int nf = 0; nf < 4; ++nf) {
        int row = wn * 64 + nf * 16 + (lane & 15);
        int off = row * 128 + (kb ^ ((row & 7) << 4));
        bfr[nf] = *(const bf16x8*)((const char*)(&lB[buf][0]) + off);
      }
#pragma unroll
      for (int mf = 0; mf < 4; ++mf)
#pragma unroll
        for (int nf = 0; nf < 4; ++nf)
          acc[mf][nf] = __builtin_amdgcn_mfma_f32_16x16x32_bf16(af[mf], bfr[nf], acc[mf][nf], 0, 0, 0);
    }
  };

  // NT=4, fully peeled, counted vmcnt (6 loads per stage)
  stage(0, 0);
  CFENCE;
  stage(1, 1);
  CFENCE;
  VMW(6);  // tile 0 landed, tile 1 flying
  RAWBAR;
  compute(0);
  RAWBAR;
  stage(0, 2);
  CFENCE;
  VMW(6);
  RAWBAR;
  compute(1);
  RAWBAR;
  stage(1, 3);
  CFENCE;
  VMW(6);
  RAWBAR;
  compute(0);
  RAWBAR;
  VMW(0);
  RAWBAR;
  compute(1);

#pragma unroll
  for (int nf = 0; nf < 4; ++nf) {
    int jcol = wn * 64 + nf * 16 + (lane & 15);
    float b3 = bias3[jcol & 63];
    int j = n0 + jcol;
#pragma unroll
    for (int mf = 0; mf < 4; ++mf) {
#pragma unroll
      for (int q = 0; q < 4; ++q) {
        size_t row = m0 + (size_t)(wm * 64 + mf * 16 + (lane >> 4) * 4 + q);
        OUT[row * 4096 + j] = acc[mf][nf][q] + b3;
      }
    }
  }
}

extern "C" void kernel_launch(void* const* d_in, const int* in_sizes, int n_in,
                              void* d_out, int out_size, void* d_ws, size_t ws_size,
                              hipStream_t stream) {
  (void)in_sizes; (void)n_in; (void)out_size; (void)ws_size;
  const float* x  = (const float*)d_in[0];
  const float* w1 = (const float*)d_in[1];
  const float* w2 = (const float*)d_in[2];
  const float* w3 = (const float*)d_in[3];
  const float* b1 = (const float*)d_in[4];
  const float* b2 = (const float*)d_in[5];
  const float* b3 = (const float*)d_in[6];
  float* out = (float*)d_out;
  char* ws = (char*)d_ws;

  // workspace layout
  float*  w2s  = (float*)(ws + 0);                   // 64 KB
  float*  c2   = (float*)(ws + 65536);               // 1 KB (+pad)
  bf16_t* w1t  = (bf16_t*)(ws + 69632);              // 2 MB  [256][4096] bf16
  bf16_t* w3pt = (bf16_t*)(ws + 69632 + 2097152);    // 2 MB  [4096][256] bf16
  bf16_t* S    = (bf16_t*)(ws + 69632 + 2 * 2097152);// 4 MB  [8192][256] bf16

  w2s_k<<<64, 256, 0, stream>>>(w2, w2s);
  prep_k<<<513, 256, 0, stream>>>(w1, w3, w2s, b1, b2, w1t, w3pt, c2);
  gemm1_k<<<512, 256, 0, stream>>>(x, w1t, c2, S);
  gemm2_k<<<1024, 512, 0, stream>>>(S, w3pt, b3, out);
}

// Round 8
// 104.463 us; speedup vs baseline: 1.2314x; 1.1806x over previous
//
#include <hip/hip_runtime.h>
#include <stdint.h>
#include <stddef.h>

typedef __bf16 bf16_t;
typedef __bf16 bf16x8 __attribute__((ext_vector_type(8)));
typedef __bf16 bf16x4 __attribute__((ext_vector_type(4)));
typedef float f32x4 __attribute__((ext_vector_type(4)));

#define VMW(n) asm volatile("s_waitcnt vmcnt(" #n ")" ::: "memory")
#define CFENCE asm volatile("" ::: "memory")
#define RAWBAR              \
  do {                      \
    __builtin_amdgcn_s_barrier(); \
    CFENCE;                 \
  } while (0)

__device__ __forceinline__ void gload_lds16(const void* g, void* l) {
  __builtin_amdgcn_global_load_lds(
      (const __attribute__((address_space(1))) uint32_t*)g,
      (__attribute__((address_space(3))) uint32_t*)l, 16, 0, 0);
}

// ---------------- w2s: w2s[r*256+m] = sum_n w2[((r*256+m)*64)+n] ----------------
__global__ __launch_bounds__(256) void w2s_k(const float* __restrict__ w2,
                                             float* __restrict__ w2s) {
  const int r = blockIdx.x, m = threadIdx.x;
  const float4* p = (const float4*)(w2 + ((size_t)(r * 256 + m)) * 64);
  float s = 0.f;
#pragma unroll
  for (int i = 0; i < 16; ++i) {
    float4 v = p[i];
    s += (v.x + v.y) + (v.z + v.w);
  }
  w2s[r * 256 + m] = s;
}

// ---------------- merged prep ----------------
// blocks 0..255:   w1t[m*4096+k] = bf16(w1[k*256+m] * w2s[(k&63)*256+m])
// blocks 256..511: w3pt[(o*64+r)*256+m] = bf16(w3[m*4096 + r*64 + o])
// block 512:       c2[m] = sum_r bias1[r]*w2s[r*256+m] + 64*bias2[m]
__global__ __launch_bounds__(256) void prep_k(
    const float* __restrict__ w1, const float* __restrict__ w3,
    const float* __restrict__ w2s, const float* __restrict__ bias1,
    const float* __restrict__ bias2, bf16_t* __restrict__ w1t,
    bf16_t* __restrict__ w3pt, float* __restrict__ c2) {
  __shared__ float lds[64][65];
  const int b = blockIdx.x;
  const int t = threadIdx.x;
  if (b == 512) {
    float s = 64.f * bias2[t];
#pragma unroll 8
    for (int r = 0; r < 64; ++r) s += bias1[r] * w2s[r * 256 + t];
    c2[t] = s;
    return;
  }
  if (b < 256) {
    const int k0 = (b >> 2) * 64;
    const int mt = (b & 3) * 64;
#pragma unroll
    for (int it = 0; it < 16; ++it) {
      int idx = t + it * 256;
      int kl = idx >> 6, ml = idx & 63;
      int k = k0 + kl;
      lds[kl][ml] = w1[(size_t)k * 256 + mt + ml] * w2s[(k & 63) * 256 + mt + ml];
    }
    __syncthreads();
#pragma unroll
    for (int it = 0; it < 16; ++it) {
      int idx = t + it * 256;
      int ml = idx >> 6, kl = idx & 63;
      w1t[(size_t)(mt + ml) * 4096 + k0 + kl] = (bf16_t)lds[kl][ml];
    }
    return;
  }
  const int b2 = b - 256;
  const int r = b2 & 63;
  const int mt = (b2 >> 6) * 64;
#pragma unroll
  for (int it = 0; it < 16; ++it) {
    int idx = t + it * 256;
    int ml = idx >> 6, o = idx & 63;
    lds[ml][o] = w3[(size_t)(mt + ml) * 4096 + r * 64 + o];
  }
  __syncthreads();
#pragma unroll
  for (int it = 0; it < 16; ++it) {
    int idx = t + it * 256;
    int o = idx >> 6, ml = idx & 63;
    w3pt[(size_t)(o * 64 + r) * 256 + mt + ml] = (bf16_t)lds[ml][o];
  }
}

// ---------------- GEMM1 (K-split 4, fat steps) ----------------
// S4[t, ks*256+n] = sum_{k in quarter ks} bf16(X[t,k]) * W1T[n,k]
// grid 512 = 8 xcd x (16 mt x 4 ks); 256 thr = 4 waves (2M x 2N), wave tile 32x128
// BM=64, BN=256, BK=64, 16 K-steps; 32 MFMA + 10 ds_read per wave-step
// LDS 80KB -> 2 blocks/CU
__global__ __launch_bounds__(256, 2) void gemm1_k(
    const float* __restrict__ X, const bf16_t* __restrict__ W1T,
    bf16_t* __restrict__ S4) {
  __shared__ __align__(16) bf16_t lA[2][64 * 64];
  __shared__ __align__(16) bf16_t lB[2][256 * 64];
  const int tid = threadIdx.x;
  const int lane = tid & 63;
  const int wv = tid >> 6;  // 0..3
  const int bid = (int)blockIdx.x;
  const int xcd = bid & 7;
  const int rest = bid >> 3;             // 0..63
  const int mtile = xcd * 16 + (rest >> 2);  // XCD x owns rows x*1024..+1023
  const int ks = rest & 3;
  const size_t m0 = (size_t)mtile * 64;
  const int kbase = ks * 1024;
  const int wm = wv >> 1, wn = wv & 1;   // 2M x 2N; wave tile 32 rows x 128 cols
  const int ar = tid >> 2;               // 0..63 A-stage row
  const int acg = tid & 3;               // A-stage col slot

  f32x4 acc[2][8];
#pragma unroll
  for (int i = 0; i < 2; ++i)
#pragma unroll
    for (int j = 0; j < 8; ++j) acc[i][j] = (f32x4){0.f, 0.f, 0.f, 0.f};

  float4 aR[4];  // A staging: 4 float4/thread (row ar, f4-slots acg+4j)

  auto issueA = [&](int kt) {
#pragma unroll
    for (int j = 0; j < 4; ++j) {
      int f4 = acg + j * 4;
      aR[j] = *(const float4*)(X + (m0 + ar) * 4096 + (size_t)(kbase + kt * 64 + f4 * 4));
    }
  };
  auto writeA = [&](int buf) {
#pragma unroll
    for (int j = 0; j < 4; ++j) {
      int f4 = acg + j * 4;
      int off = ar * 128 + ((f4 * 8) ^ ((ar & 7) << 4));
      bf16x4 v;
      v[0] = (bf16_t)aR[j].x;
      v[1] = (bf16_t)aR[j].y;
      v[2] = (bf16_t)aR[j].z;
      v[3] = (bf16_t)aR[j].w;
      *(bf16x4*)((char*)(&lA[buf][0]) + off) = v;
    }
  };
  auto issueB = [&](int buf, int kt) {
#pragma unroll
    for (int i = 0; i < 8; ++i) {
      int row = wv * 64 + i * 8 + (lane >> 3);
      int srckb = ((lane & 7) * 16) ^ ((row & 7) << 4);
      const char* src = (const char*)W1T + (size_t)row * 8192 + (size_t)(kbase + kt * 64) * 2 + srckb;
      char* dst = (char*)(&lB[buf][0]) + (wv * 64 + i * 8) * 128;  // wave-uniform base
      gload_lds16(src, dst);
    }
  };
  auto compute = [&](int buf) {
#pragma unroll
    for (int kk = 0; kk < 2; ++kk) {
      const int kb = kk * 64 + ((lane >> 4) * 16);
      bf16x8 af[2], bfr[8];
#pragma unroll
      for (int mf = 0; mf < 2; ++mf) {
        int row = wm * 32 + mf * 16 + (lane & 15);
        int off = row * 128 + (kb ^ ((row & 7) << 4));
        af[mf] = *(const bf16x8*)((const char*)(&lA[buf][0]) + off);
      }
#pragma unroll
      for (int nf = 0; nf < 8; ++nf) {
        int row = wn * 128 + nf * 16 + (lane & 15);
        int off = row * 128 + (kb ^ ((row & 7) << 4));
        bfr[nf] = *(const bf16x8*)((const char*)(&lB[buf][0]) + off);
      }
#pragma unroll
      for (int mf = 0; mf < 2; ++mf)
#pragma unroll
        for (int nf = 0; nf < 8; ++nf)
          acc[mf][nf] = __builtin_amdgcn_mfma_f32_16x16x32_bf16(af[mf], bfr[nf], acc[mf][nf], 0, 0, 0);
    }
  };

  // prologue
  issueA(0);
  issueB(0, 0);
  writeA(0);         // compiler inserts vmcnt wait on A-loads
  __syncthreads();   // drains B(0) gload_lds

  // m97 2-barrier loop, 16 fat steps
#pragma unroll 1
  for (int kt = 0; kt < 16; ++kt) {
    int cur = kt & 1;
    bool more = (kt + 1) < 16;
    if (more) {
      issueA(kt + 1);          // X read (HBM) issued early
      issueB(cur ^ 1, kt + 1); // async direct-to-LDS
    }
    compute(cur);
    if (more) writeA(cur ^ 1);
    __syncthreads();
  }

  // epilogue: partial sums
#pragma unroll
  for (int nf = 0; nf < 8; ++nf) {
    int col = wn * 128 + nf * 16 + (lane & 15);
#pragma unroll
    for (int mf = 0; mf < 2; ++mf) {
#pragma unroll
      for (int q = 0; q < 4; ++q) {
        int row = wm * 32 + mf * 16 + (lane >> 4) * 4 + q;
        S4[(m0 + row) * 1024 + (size_t)(ks * 256 + col)] = (bf16_t)acc[mf][nf][q];
      }
    }
  }
}

// ---------------- reduce: S[t,m] = bf16( sum_h S4[t, h*256+m] + c2[m] )
// grid 1024; XCD-aligned: x = bid&7 handles rows x*1024 + (bid>>3)*8 .. +7
__global__ __launch_bounds__(256) void reduce_k(
    const bf16_t* __restrict__ S4, const float* __restrict__ c2,
    bf16_t* __restrict__ S) {
  const int bid = (int)blockIdx.x;
  const int base = (bid & 7) * 1024 + (bid >> 3) * 8;
  const int t = threadIdx.x;
  const int row = base + (t >> 5);
  const int c8 = (t & 31) << 3;
  float s[8];
  float4 ca = *(const float4*)(c2 + c8);
  float4 cb = *(const float4*)(c2 + c8 + 4);
  s[0] = ca.x; s[1] = ca.y; s[2] = ca.z; s[3] = ca.w;
  s[4] = cb.x; s[5] = cb.y; s[6] = cb.z; s[7] = cb.w;
#pragma unroll
  for (int h = 0; h < 4; ++h) {
    bf16x8 v = *(const bf16x8*)(S4 + (size_t)row * 1024 + h * 256 + c8);
#pragma unroll
    for (int j = 0; j < 8; ++j) s[j] += (float)v[j];
  }
  bf16x8 o;
#pragma unroll
  for (int j = 0; j < 8; ++j) o[j] = (bf16_t)s[j];
  *(bf16x8*)(S + (size_t)row * 256 + c8) = o;
}

// ---------------- GEMM2: OUT[t, j] = sum_{m=0..255} S[t,m] * W3pT[j, m] + bias3[j&63]
// grid 1024 = 8 xcd x 8 mt x 16 nt; 512 threads = 8 waves (2M x 4N), wave tile 64x64
// BM=128, BN=256, BK=64, NT=4; both operands via global_load_lds; counted vmcnt
__global__ __launch_bounds__(512, 2) void gemm2_k(
    const bf16_t* __restrict__ S, const bf16_t* __restrict__ W3pT,
    const float* __restrict__ bias3, float* __restrict__ OUT) {
  __shared__ __align__(16) bf16_t lA[2][128 * 64];
  __shared__ __align__(16) bf16_t lB[2][256 * 64];
  const int tid = threadIdx.x;
  const int lane = tid & 63;
  const int wv = tid >> 6;
  const int bid = (int)blockIdx.x;
  const int xcd = bid & 7;
  const int rest = bid >> 3;            // 0..127
  const int mt = xcd * 8 + (rest >> 4); // rows xcd*1024..+1023 (matches writers)
  const int nt = rest & 15;
  const size_t m0 = (size_t)mt * 128;
  const int n0 = nt * 256;
  const int wm = wv >> 2, wn = wv & 3;

  f32x4 acc[4][4];
#pragma unroll
  for (int i = 0; i < 4; ++i)
#pragma unroll
    for (int j = 0; j < 4; ++j) acc[i][j] = (f32x4){0.f, 0.f, 0.f, 0.f};

  auto stage = [&](int buf, int kt) {
#pragma unroll
    for (int i = 0; i < 2; ++i) {
      int row = wv * 16 + i * 8 + (lane >> 3);
      int srckb = ((lane & 7) * 16) ^ ((row & 7) << 4);
      const char* srcA = (const char*)S + (m0 + row) * 512 + (size_t)(kt * 128) + srckb;
      char* dstA = (char*)(&lA[buf][0]) + (wv * 16 + i * 8) * 128;
      gload_lds16(srcA, dstA);
    }
#pragma unroll
    for (int i = 0; i < 4; ++i) {
      int row = wv * 32 + i * 8 + (lane >> 3);
      int srckb = ((lane & 7) * 16) ^ ((row & 7) << 4);
      const char* srcB = (const char*)W3pT + (size_t)(n0 + row) * 512 + (size_t)(kt * 128) + srckb;
      char* dstB = (char*)(&lB[buf][0]) + (wv * 32 + i * 8) * 128;
      gload_lds16(srcB, dstB);
    }
  };
  auto compute = [&](int buf) {
#pragma unroll
    for (int kk = 0; kk < 2; ++kk) {
      const int kb = kk * 64 + ((lane >> 4) * 16);
      bf16x8 af[4], bfr[4];
#pragma unroll
      for (int mf = 0; mf < 4; ++mf) {
        int row = wm * 64 + mf * 16 + (lane & 15);
        int off = row * 128 + (kb ^ ((row & 7) << 4));
        af[mf] = *(const bf16x8*)((const char*)(&lA[buf][0]) + off);
      }
#pragma unroll
      for (int nf = 0; nf < 4; ++nf) {
        int row = wn * 64 + nf * 16 + (lane & 15);
        int off = row * 128 + (kb ^ ((row & 7) << 4));
        bfr[nf] = *(const bf16x8*)((const char*)(&lB[buf][0]) + off);
      }
#pragma unroll
      for (int mf = 0; mf < 4; ++mf)
#pragma unroll
        for (int nf = 0; nf < 4; ++nf)
          acc[mf][nf] = __builtin_amdgcn_mfma_f32_16x16x32_bf16(af[mf], bfr[nf], acc[mf][nf], 0, 0, 0);
    }
  };

  // NT=4, fully peeled, counted vmcnt (6 loads per stage)
  stage(0, 0);
  CFENCE;
  stage(1, 1);
  CFENCE;
  VMW(6);  // tile 0 landed, tile 1 flying
  RAWBAR;
  compute(0);
  RAWBAR;
  stage(0, 2);
  CFENCE;
  VMW(6);
  RAWBAR;
  compute(1);
  RAWBAR;
  stage(1, 3);
  CFENCE;
  VMW(6);
  RAWBAR;
  compute(0);
  RAWBAR;
  VMW(0);
  RAWBAR;
  compute(1);

#pragma unroll
  for (int nf = 0; nf < 4; ++nf) {
    int jcol = wn * 64 + nf * 16 + (lane & 15);
    float b3 = bias3[jcol & 63];
    int j = n0 + jcol;
#pragma unroll
    for (int mf = 0; mf < 4; ++mf) {
#pragma unroll
      for (int q = 0; q < 4; ++q) {
        size_t row = m0 + (size_t)(wm * 64 + mf * 16 + (lane >> 4) * 4 + q);
        OUT[row * 4096 + j] = acc[mf][nf][q] + b3;
      }
    }
  }
}

extern "C" void kernel_launch(void* const* d_in, const int* in_sizes, int n_in,
                              void* d_out, int out_size, void* d_ws, size_t ws_size,
                              hipStream_t stream) {
  (void)in_sizes; (void)n_in; (void)out_size; (void)ws_size;
  const float* x  = (const float*)d_in[0];
  const float* w1 = (const float*)d_in[1];
  const float* w2 = (const float*)d_in[2];
  const float* w3 = (const float*)d_in[3];
  const float* b1 = (const float*)d_in[4];
  const float* b2 = (const float*)d_in[5];
  const float* b3 = (const float*)d_in[6];
  float* out = (float*)d_out;
  char* ws = (char*)d_ws;

  // workspace layout
  float*  w2s  = (float*)(ws + 0);                   // 64 KB
  float*  c2   = (float*)(ws + 65536);               // 1 KB (+pad)
  bf16_t* w1t  = (bf16_t*)(ws + 69632);              // 2 MB  [256][4096] bf16
  bf16_t* w3pt = (bf16_t*)(ws + 69632 + 2097152);    // 2 MB  [4096][256] bf16
  bf16_t* S4   = (bf16_t*)(ws + 69632 + 2 * 2097152);               // 16 MB [8192][1024]
  bf16_t* S    = (bf16_t*)(ws + 69632 + 2 * 2097152 + 16777216);    // 4 MB  [8192][256]

  w2s_k<<<64, 256, 0, stream>>>(w2, w2s);
  prep_k<<<513, 256, 0, stream>>>(w1, w3, w2s, b1, b2, w1t, w3pt, c2);
  gemm1_k<<<512, 256, 0, stream>>>(x, w1t, S4);
  reduce_k<<<1024, 256, 0, stream>>>(S4, c2, S);
  gemm2_k<<<1024, 512, 0, stream>>>(S, w3pt, b3, out);
}